// Round 9
// baseline (31.093 us; speedup 1.0000x reference)
//
#include <hip/hip_runtime.h>
#include <math.h>

// Problem constants
constexpr int NT = 32;      // components
constexpr int ND = 1024;    // dim
constexpr int NB = 4096;    // batch
constexpr int NSLICE = 8;   // d-slices (128 d each)
constexpr int NRG   = 64;   // row-groups (64 rows each)
constexpr int NBLK_MID = 256;

// Workspace layout (float offsets)
//  ivc : [256][32][4] chunk-major inv_var            @ 0        (32768)
//  m2c : [256][32][4] chunk-major (-2*mu*inv_var)    @ 32768    (32768)
//  c2  : [32]  sum(mu^2*inv_var)                     @ 65536    (32)
//  klg : [B][T]                                      @ 65600    (131072)
//  lpi : [B][T]                                      @ 196672   (131072)
//  qp  : [8][4096][32] per-slice partial quads       @ 327744   (1048576)
//  Pg  : [256][32] per-mid-block partial sum klg     @ 1376320  (8192)
//  Pp  : [256][32] per-mid-block partial sum lpi     @ 1384512  (8192)
constexpr int OFF_M2C = 32768;
constexpr int OFF_C2  = 65536;
constexpr int OFF_KLG = 65600;
constexpr int OFF_LPI = 196672;
constexpr int OFF_QP  = 327744;
constexpr int OFF_PG  = 1376320;
constexpr int OFF_PP  = 1384512;

// ---------------------------------------------------------------------------
// Kernel A: per-component stats + zero out[0].
// grid = 32 (one block per component t), block = 256 (one chunk of 4 d's each)
// ---------------------------------------------------------------------------
__global__ __launch_bounds__(256) void k_stats(const float* __restrict__ mu,
                                               const float* __restrict__ rho,
                                               float* __restrict__ ws,
                                               float* __restrict__ out) {
  float* ivc = ws;
  float* m2c = ws + OFF_M2C;
  float* c2  = ws + OFF_C2;

  const int t = blockIdx.x;
  const int c = threadIdx.x;  // chunk index 0..255 (covers d = 4c..4c+3)

  float4 mu4  = reinterpret_cast<const float4*>(mu  + t * ND)[c];
  float4 rho4 = reinterpret_cast<const float4*>(rho + t * ND)[c];

  float rr[4] = {rho4.x, rho4.y, rho4.z, rho4.w};
  float mm[4] = {mu4.x,  mu4.y,  mu4.z,  mu4.w};
  float iv[4], m2[4];
  float c2p = 0.0f;
#pragma unroll
  for (int j = 0; j < 4; ++j) {
    float sd  = log1pf(expf(rr[j]));   // softplus
    float ivv = 1.0f / (sd * sd);
    iv[j] = ivv;
    m2[j] = -2.0f * mm[j] * ivv;
    c2p  += mm[j] * mm[j] * ivv;
  }
  float4 iv4 = {iv[0], iv[1], iv[2], iv[3]};
  float4 m24 = {m2[0], m2[1], m2[2], m2[3]};
  reinterpret_cast<float4*>(ivc)[c * NT + t] = iv4;   // chunk-major
  reinterpret_cast<float4*>(m2c)[c * NT + t] = m24;

  // block reduction of c2p (4 waves)
#pragma unroll
  for (int m = 32; m >= 1; m >>= 1) c2p += __shfl_xor(c2p, m, 64);
  __shared__ float red[4];
  const int wave = threadIdx.x >> 6, lane = threadIdx.x & 63;
  if (lane == 0) red[wave] = c2p;
  __syncthreads();
  if (threadIdx.x == 0) {
    c2[t] = red[0] + red[1] + red[2] + red[3];
    if (t == 0) out[0] = 0.0f;   // must re-zero every launch (graph replays)
  }
}

// ---------------------------------------------------------------------------
// Kernel B v7 "slice GEMM": block (s, rg) computes partial quads for
// d-slice s (128 d's = 32 chunks) x 64 rows. iv/m2 for the slice staged ONCE
// into LDS (32 KB) and reused by all 64 rows -> iv/m2 global traffic
// 128 MB -> 16 MB (the cross-round ~20 us invariant). Slices partition d, so
// x is still read exactly once (16.8 MB HBM). Inner loop: LDS only.
// grid = 512 (bid = s*64 + rg; slice-siblings share bid%8 -> same XCD L2),
// block = 512 threads (8 waves; wave q owns rows q*8..q*8+7).
// LDS 64 KB -> 2 blocks/CU = 4 waves/SIMD.
// ---------------------------------------------------------------------------
__global__ __launch_bounds__(512, 4) void k_slice(const float* __restrict__ x,
                                                  float* __restrict__ ws) {
  float* qp = ws + OFF_QP;

  const int bid   = blockIdx.x;
  const int slice = bid >> 6;        // 0..7
  const int rg    = bid & 63;        // 0..63
  const int tid   = threadIdx.x;

  __shared__ float xs[64 * 128];     // 32 KB [row][d-in-slice]
  __shared__ float ivs[32 * 32 * 4]; // 16 KB slice of ivc (chunk-major)
  __shared__ float m2s[32 * 32 * 4]; // 16 KB slice of m2c

  // ---- Stage x: rows rg*64..+63, d-cols slice*128..+127 (float4 j=0..31) --
  {
    const float4* xg4 = reinterpret_cast<const float4*>(x);
    float4* xs4w = reinterpret_cast<float4*>(xs);
    const int row = tid >> 3;        // 0..63
    const int j0  = tid & 7;         // 0..7
#pragma unroll
    for (int p = 0; p < 4; ++p) {
      const int j = j0 + 8 * p;
      xs4w[row * 32 + j] =
          xg4[(size_t)(rg * 64 + row) * 256 + slice * 32 + j];
    }
  }
  // ---- Stage iv/m2 slice: 1024 float4 each, linear coalesced ----
  {
    const float4* ivg = reinterpret_cast<const float4*>(ws) + (size_t)slice * 1024;
    const float4* m2g = reinterpret_cast<const float4*>(ws + OFF_M2C) + (size_t)slice * 1024;
    float4* ivw = reinterpret_cast<float4*>(ivs);
    float4* m2w = reinterpret_cast<float4*>(m2s);
    ivw[tid]       = ivg[tid];
    ivw[tid + 512] = ivg[tid + 512];
    m2w[tid]       = m2g[tid];
    m2w[tid + 512] = m2g[tid + 512];
  }
  __syncthreads();

  // ---- FMA loop: everything from LDS ----
  const int q    = tid >> 6;         // wave -> rows q*8..q*8+7
  const int lane = tid & 63;
  const int h = lane >> 5, t = lane & 31;
  const float4* ivs4 = reinterpret_cast<const float4*>(ivs);
  const float4* m2s4 = reinterpret_cast<const float4*>(m2s);
  const float4* xsr  = reinterpret_cast<const float4*>(xs) + (size_t)(q * 8) * 32;

  float a[8] = {0.f, 0.f, 0.f, 0.f, 0.f, 0.f, 0.f, 0.f};
#pragma unroll 2
  for (int i = 0; i < 16; ++i) {
    const int c = h * 16 + i;        // chunk within slice (0..31)
    float4 iv4 = ivs4[c * 32 + t];
    float4 m24 = m2s4[c * 32 + t];
#pragma unroll
    for (int r = 0; r < 8; ++r) {
      float4 xv = xsr[r * 32 + c];   // broadcast ds_read_b128
      a[r] = fmaf(xv.x, fmaf(xv.x, iv4.x, m24.x), a[r]);
      a[r] = fmaf(xv.y, fmaf(xv.y, iv4.y, m24.y), a[r]);
      a[r] = fmaf(xv.z, fmaf(xv.z, iv4.z, m24.z), a[r]);
      a[r] = fmaf(xv.w, fmaf(xv.w, iv4.w, m24.w), a[r]);
    }
  }
  // combine the two 64-d sub-halves of the slice
#pragma unroll
  for (int r = 0; r < 8; ++r) a[r] += __shfl_xor(a[r], 32, 64);

  // ---- Store partial quads: plain coalesced 128B rows, no atomics ----
  if (h == 0) {
#pragma unroll
    for (int r = 0; r < 8; ++r) {
      const int row = rg * 64 + q * 8 + r;
      qp[((size_t)slice * NB + row) * NT + t] = a[r];
    }
  }
}

// ---------------------------------------------------------------------------
// Kernel C "mid": combine the 8 slice partials -> kv; beta scan -> log_pi;
// store klg/lpi; per-block partial sums -> Pg/Pp (plain stores).
// grid = 256, block = 512 (16 rows/block; thread = (row-in-block, t))
// ---------------------------------------------------------------------------
__global__ __launch_bounds__(512) void k_mid(const float* __restrict__ beta,
                                             float* __restrict__ ws) {
  const float* c2 = ws + OFF_C2;
  const float* qp = ws + OFF_QP;
  float* klg = ws + OFF_KLG;
  float* lpi = ws + OFF_LPI;
  float* Pg  = ws + OFF_PG;
  float* Pp  = ws + OFF_PP;

  const int tid = threadIdx.x;
  const int rr = tid >> 5, t = tid & 31;
  const int row = blockIdx.x * 16 + rr;

  float quad = 0.f;
#pragma unroll
  for (int s = 0; s < NSLICE; ++s)
    quad += qp[((size_t)s * NB + row) * NT + t];

  // kl_gaussian = log_pdfs + entropy = D/2 - 0.5*quad (log_std_sum cancels)
  const float kv = 512.0f - 0.5f * (quad + c2[t]);
  klg[(size_t)row * NT + t] = kv;

  // log_pi: exclusive prefix scan of log1p(-beta) within each 32-lane group
  const float b = beta[(size_t)row * NT + t];
  const float l1m = log1pf(-b);
  float s = l1m;
#pragma unroll
  for (int d = 1; d < 32; d <<= 1) {
    float v = __shfl_up(s, (unsigned)d, 32);
    if (t >= d) s += v;
  }
  const float lp = logf(b) + (s - l1m);
  lpi[(size_t)row * NT + t] = lp;

  __shared__ float klP[16][32], lpP[16][32];
  klP[rr][t] = kv;
  lpP[rr][t] = lp;
  __syncthreads();
  if (tid < 32) {
    float sg = 0.f, sp = 0.f;
#pragma unroll
    for (int r = 0; r < 16; ++r) { sg += klP[r][tid]; sp += lpP[r][tid]; }
    Pg[(size_t)blockIdx.x * NT + tid] = sg;
    Pp[(size_t)blockIdx.x * NT + tid] = sp;
  }
}

// ---------------------------------------------------------------------------
// Kernel D: redundant per-block reduce of Pg/Pp (no atomics), then mix,
// softmax over T, weighted mean.
// grid = 256, block = 512 (8 waves; 16 rows/block, one per 32-lane group)
// ---------------------------------------------------------------------------
__global__ __launch_bounds__(512) void k_final(const float* __restrict__ ws,
                                               float* __restrict__ out) {
  const float* klg = ws + OFF_KLG;
  const float* lpi = ws + OFF_LPI;
  const float* Pg  = ws + OFF_PG;
  const float* Pp  = ws + OFF_PP;

  const int tid  = threadIdx.x;
  const int wave = tid >> 6, lane = tid & 63;
  const int t = tid & 31;        // component
  const int g = tid >> 5;        // reduce group 0..15 / row-in-block

  __shared__ float ngF[32], npF[32];
  __shared__ float redG[8][32], redP[8][32];
  __shared__ float red[8];

  // ---- Prologue: reduce the 256 per-mid-block partials (redundant) ----
  {
    float sg = 0.f, sp = 0.f;
#pragma unroll 4
    for (int b = g; b < NBLK_MID; b += 16) {
      sg += Pg[(size_t)b * NT + t];
      sp += Pp[(size_t)b * NT + t];
    }
    sg += __shfl_xor(sg, 32, 64);
    sp += __shfl_xor(sp, 32, 64);
    if (lane < 32) { redG[wave][t] = sg; redP[wave][t] = sp; }
  }
  __syncthreads();
  if (tid < 32) {
    float ng = 0.f, np = 0.f;
#pragma unroll
    for (int w = 0; w < 8; ++w) { ng += redG[w][tid]; np += redP[w][tid]; }
    ngF[tid] = ng;
    npF[tid] = np;
  }
  __syncthreads();

  // ---- mix + softmax over T + weighted mean ----
  const int row = blockIdx.x * 16 + g;
  const float kg = klg[(size_t)row * NT + t];
  const float lp = lpi[(size_t)row * NT + t];
  const float ng = ngF[t], np = npF[t];
  const float mix  = np / (ng + np);
  const float klgm = mix * kg;
  const float kl   = klgm + (1.0f - mix) * lp;

  float m = kl;
#pragma unroll
  for (int mk = 16; mk >= 1; mk >>= 1) m = fmaxf(m, __shfl_xor(m, mk, 64));
  const float e = expf(kl - m);
  float num = e * klgm, den = e;
#pragma unroll
  for (int mk = 16; mk >= 1; mk >>= 1) {
    num += __shfl_xor(num, mk, 64);
    den += __shfl_xor(den, mk, 64);
  }
  float s = num / den;           // per-row sum_t phi*klgm (replicated in group)
  s += __shfl_xor(s, 32, 64);    // combine the wave's two rows

  if (lane == 0) red[wave] = s;
  __syncthreads();
  if (tid == 0) {
    float tot = 0.f;
#pragma unroll
    for (int w = 0; w < 8; ++w) tot += red[w];
    atomicAdd(out, tot * (1.0f / (float)NB));
  }
}

// ---------------------------------------------------------------------------
extern "C" void kernel_launch(void* const* d_in, const int* in_sizes, int n_in,
                              void* d_out, int out_size, void* d_ws, size_t ws_size,
                              hipStream_t stream) {
  const float* x    = (const float*)d_in[0];
  const float* mu   = (const float*)d_in[1];
  const float* rho  = (const float*)d_in[2];
  const float* beta = (const float*)d_in[3];
  float* out = (float*)d_out;
  float* ws  = (float*)d_ws;

  hipLaunchKernelGGL(k_stats, dim3(32),  dim3(256), 0, stream, mu, rho, ws, out);
  hipLaunchKernelGGL(k_slice, dim3(NSLICE * NRG), dim3(512), 0, stream, x, ws);
  hipLaunchKernelGGL(k_mid,   dim3(NBLK_MID), dim3(512), 0, stream, beta, ws);
  hipLaunchKernelGGL(k_final, dim3(256), dim3(512), 0, stream, ws, out);
}